// Round 2
// 149.196 us; speedup vs baseline: 1.1975x; 1.1975x over previous
//
#include <hip/hip_runtime.h>

#define N_ROWS 65536
#define DIM 256
#define K_EMB 1024

typedef short bf16x8 __attribute__((ext_vector_type(8)));
typedef float f32x4 __attribute__((ext_vector_type(4)));

__device__ static inline unsigned short f2bf(float f) {
    unsigned int u = __float_as_uint(f);
    return (unsigned short)((u + 0x7fffu + ((u >> 16) & 1u)) >> 16);   // RNE
}

__device__ static inline void async16(const void* g, void* l) {
    __builtin_amdgcn_global_load_lds(
        (const __attribute__((address_space(1))) void*)g,
        (__attribute__((address_space(3))) void*)l, 16, 0, 0);
}

// ---------------- Kernel B: emb -> bf16 + half-norms + zero accum ---------------
__global__ __launch_bounds__(256)
void emb_prep_kernel(const float* __restrict__ emb, unsigned short* __restrict__ eb,
                     float* __restrict__ hn, float* __restrict__ loss_accum) {
    if (blockIdx.x == 0 && threadIdx.x == 0) loss_accum[0] = 0.0f;
    int wave = (blockIdx.x * 256 + threadIdx.x) >> 6;   // 1024 waves, one per emb row
    int lane = threadIdx.x & 63;
    float4 v = reinterpret_cast<const float4*>(emb + (size_t)wave * DIM)[lane];
    float s = v.x * v.x + v.y * v.y + v.z * v.z + v.w * v.w;
    #pragma unroll
    for (int off = 32; off > 0; off >>= 1) s += __shfl_xor(s, off, 64);
    if (lane == 0) hn[wave] = 0.5f * s;
    ushort4 w = { f2bf(v.x), f2bf(v.y), f2bf(v.z), f2bf(v.w) };
    *reinterpret_cast<ushort4*>(eb + (size_t)wave * DIM + lane * 4) = w;
}

// ---------------- Fused kernel: convert + MFMA argmax + gather + loss -----------
// Block: 128 rows x ALL 1024 cols. 4 waves, 32 rows/wave.
// A (K=256) loaded fp32 straight from x into fragment layout, converted in-reg
// (no xb array, no LDS A-stage). B swept in 16 chunks of 64 cols, double-buffered
// via global_load_lds prefetch (identical pipeline to the proven argmax kernel).
// Loss computed the PROVEN way: fp32 re-read of x in the gather phase, direct
// ||q-x||^2 accumulation (round-0 gather_loss logic, fused in).
// LDS: B bufs [0,32K)+[32K,64K); hn [64K,68K); idxs [68K..); partials.
__global__ __launch_bounds__(256, 2)
void vq_fused_kernel(const float* __restrict__ x, const float* __restrict__ emb,
                     const unsigned short* __restrict__ eb,
                     const float* __restrict__ hn,
                     float* __restrict__ out, float* __restrict__ loss_accum) {
    __shared__ __align__(16) char smem[70656];
    float* hns     = reinterpret_cast<float*>(smem + 65536);
    int*   idxs    = reinterpret_cast<int*>(smem + 69632);    // 128 ints
    float* partial = reinterpret_cast<float*>(smem + 70144);  // 4 floats

    const int t    = threadIdx.x;
    const int w    = t >> 6, lane = t & 63;
    const int q    = lane >> 4, l15 = lane & 15;
    const int n0   = blockIdx.x * 128;

    #pragma unroll
    for (int i = 0; i < 4; ++i) hns[t + i * 256] = hn[t + i * 256];

    // ---- per-thread B staging constants (swizzled) ----
    const unsigned short* egp[4];
    int ldsB[4];
    #pragma unroll
    for (int i = 0; i < 4; ++i) {
        int s  = i * 512 + t;
        int c  = s >> 5;
        int pk = (s & 24) | ((s ^ c) & 7);
        egp[i]  = eb + (size_t)c * DIM + pk * 8;
        ldsB[i] = (i * 512 + w * 64) * 16;
    }
    // prefetch B chunk 0 -> buf0 (in flight during the x load/convert below)
    #pragma unroll
    for (int i = 0; i < 4; ++i) async16(egp[i], smem + ldsB[i]);

    // ---- load x fp32 directly into A fragments, convert to bf16 ----
    // a[mt][ks] = x_bf16[row = w*32+mt*16+l15, cols (ks*4+q)*8 .. +7]
    bf16x8 a[2][8];
    const float* xrow = x + (size_t)(n0 + w * 32 + l15) * DIM + q * 8;
    #pragma unroll
    for (int mt = 0; mt < 2; ++mt) {
        #pragma unroll
        for (int ks = 0; ks < 8; ++ks) {
            const float4* p = reinterpret_cast<const float4*>(xrow + mt * 16 * DIM + ks * 32);
            float4 v0 = p[0], v1 = p[1];
            bf16x8 av;
            av[0] = (short)f2bf(v0.x); av[1] = (short)f2bf(v0.y);
            av[2] = (short)f2bf(v0.z); av[3] = (short)f2bf(v0.w);
            av[4] = (short)f2bf(v1.x); av[5] = (short)f2bf(v1.y);
            av[6] = (short)f2bf(v1.z); av[7] = (short)f2bf(v1.w);
            a[mt][ks] = av;
        }
    }

    // B-frag LDS offsets: col stride 512B; swizzle depends only on l15 (c&7==l15&7)
    int soff[8];
    #pragma unroll
    for (int ks = 0; ks < 8; ++ks) {
        int pk = ks * 4 + q;
        soff[ks] = ((pk & 24) | ((pk ^ l15) & 7)) * 16;
    }
    int cb[4];
    #pragma unroll
    for (int nt = 0; nt < 4; ++nt) cb[nt] = (nt * 16 + l15) * 512;

    float best[8];
    int   bidx[8];
    #pragma unroll
    for (int i = 0; i < 8; ++i) { best[i] = -1e30f; bidx[i] = 0; }

    for (int c = 0; c < 16; ++c) {
        __syncthreads();   // chunk c staged; prior readers of other buf done
        const char* buf = smem + (c & 1) * 32768;
        if (c < 15) {      // prefetch chunk c+1 into the buffer freed at the barrier
            int nb = ((c + 1) & 1) * 32768;
            #pragma unroll
            for (int i = 0; i < 4; ++i)
                async16(egp[i] + (c + 1) * 64 * DIM, smem + nb + ldsB[i]);
        }
        f32x4 acc[2][4];
        #pragma unroll
        for (int nt = 0; nt < 4; ++nt) {
            float h = -hns[c * 64 + nt * 16 + l15];
            f32x4 in4 = {h, h, h, h};
            acc[0][nt] = in4; acc[1][nt] = in4;
        }
        #pragma unroll
        for (int ks = 0; ks < 8; ++ks) {
            bf16x8 b0 = *reinterpret_cast<const bf16x8*>(buf + cb[0] + soff[ks]);
            bf16x8 b1 = *reinterpret_cast<const bf16x8*>(buf + cb[1] + soff[ks]);
            bf16x8 b2 = *reinterpret_cast<const bf16x8*>(buf + cb[2] + soff[ks]);
            bf16x8 b3 = *reinterpret_cast<const bf16x8*>(buf + cb[3] + soff[ks]);
            acc[0][0] = __builtin_amdgcn_mfma_f32_16x16x32_bf16(a[0][ks], b0, acc[0][0], 0, 0, 0);
            acc[1][0] = __builtin_amdgcn_mfma_f32_16x16x32_bf16(a[1][ks], b0, acc[1][0], 0, 0, 0);
            acc[0][1] = __builtin_amdgcn_mfma_f32_16x16x32_bf16(a[0][ks], b1, acc[0][1], 0, 0, 0);
            acc[1][1] = __builtin_amdgcn_mfma_f32_16x16x32_bf16(a[1][ks], b1, acc[1][1], 0, 0, 0);
            acc[0][2] = __builtin_amdgcn_mfma_f32_16x16x32_bf16(a[0][ks], b2, acc[0][2], 0, 0, 0);
            acc[1][2] = __builtin_amdgcn_mfma_f32_16x16x32_bf16(a[1][ks], b2, acc[1][2], 0, 0, 0);
            acc[0][3] = __builtin_amdgcn_mfma_f32_16x16x32_bf16(a[0][ks], b3, acc[0][3], 0, 0, 0);
            acc[1][3] = __builtin_amdgcn_mfma_f32_16x16x32_bf16(a[1][ks], b3, acc[1][3], 0, 0, 0);
        }
        // epilogue: scores already include -0.5||e||^2; cols ascend -> strict >
        #pragma unroll
        for (int nt = 0; nt < 4; ++nt) {
            int k = c * 64 + nt * 16 + l15;
            #pragma unroll
            for (int mt = 0; mt < 2; ++mt)
                #pragma unroll
                for (int r = 0; r < 4; ++r) {
                    float sc = acc[mt][nt][r];
                    int slot = mt * 4 + r;
                    if (sc > best[slot]) { best[slot] = sc; bidx[slot] = k; }
                }
        }
    }

    // butterfly argmax across the 16 l15 lanes (lowest index wins ties)
    #pragma unroll
    for (int slot = 0; slot < 8; ++slot) {
        float bs = best[slot]; int bi = bidx[slot];
        #pragma unroll
        for (int off = 8; off >= 1; off >>= 1) {
            float os = __shfl_xor(bs, off, 64);
            int   oi = __shfl_xor(bi, off, 64);
            if (os > bs || (os == bs && oi < bi)) { bs = os; bi = oi; }
        }
        if (l15 == 0) {
            int mt = slot >> 2, r = slot & 3;
            idxs[w * 32 + mt * 16 + q * 4 + r] = bi;
        }
    }

    // gather quantized rows (fp32 emb, L2/L3-resident), write output, and
    // accumulate the loss DIRECTLY from fp32 x re-read (proven round-0 path).
    float s = 0.0f;
    #pragma unroll 4
    for (int i = 0; i < 32; ++i) {
        int n = n0 + w * 32 + i;
        int k = __builtin_amdgcn_readfirstlane(idxs[w * 32 + i]);
        float4 qv = *reinterpret_cast<const float4*>(emb + (size_t)k * DIM + lane * 4);
        float4 xv = *reinterpret_cast<const float4*>(x + (size_t)n * DIM + lane * 4);
        *reinterpret_cast<float4*>(out + (size_t)n * DIM + lane * 4) = qv;
        float dx = qv.x - xv.x, dy = qv.y - xv.y, dz = qv.z - xv.z, dw = qv.w - xv.w;
        s += dx * dx + dy * dy + dz * dz + dw * dw;
    }
    #pragma unroll
    for (int off = 32; off > 0; off >>= 1) s += __shfl_xor(s, off, 64);
    if (lane == 0) partial[w] = s;
    __syncthreads();
    if (t == 0)
        atomicAdd(loss_accum, partial[0] + partial[1] + partial[2] + partial[3]);
}

// ---------------- finalize loss --------------------------------------------------
__global__ void finalize_kernel(const float* __restrict__ loss_accum,
                                float* __restrict__ out_loss) {
    if (threadIdx.x == 0)
        out_loss[0] = 1.25f * loss_accum[0] / 16777216.0f;
}

extern "C" void kernel_launch(void* const* d_in, const int* in_sizes, int n_in,
                              void* d_out, int out_size, void* d_ws, size_t ws_size,
                              hipStream_t stream) {
    const float* x   = reinterpret_cast<const float*>(d_in[0]);
    const float* emb = reinterpret_cast<const float*>(d_in[1]);
    float* out       = reinterpret_cast<float*>(d_out);
    float* loss_out  = out + (size_t)N_ROWS * DIM;

    char* ws = reinterpret_cast<char*>(d_ws);
    float*          loss_accum = reinterpret_cast<float*>(ws);            // 256 B
    float*          hn         = reinterpret_cast<float*>(ws + 4096);     // 4 KB
    unsigned short* eb         = reinterpret_cast<unsigned short*>(ws + 8192); // 512 KB

    emb_prep_kernel<<<K_EMB / 4, 256, 0, stream>>>(emb, eb, hn, loss_accum);
    vq_fused_kernel<<<N_ROWS / 128, 256, 0, stream>>>(x, emb, eb, hn, out, loss_accum);
    finalize_kernel<<<1, 64, 0, stream>>>(loss_accum, loss_out);
}

// Round 4
// 147.865 us; speedup vs baseline: 1.2082x; 1.0090x over previous
//
#include <hip/hip_runtime.h>

#define N_ROWS 65536
#define DIM 256
#define K_EMB 1024

typedef short bf16x8 __attribute__((ext_vector_type(8)));
typedef float f32x4 __attribute__((ext_vector_type(4)));

__device__ static inline unsigned short f2bf(float f) {
    unsigned int u = __float_as_uint(f);
    return (unsigned short)((u + 0x7fffu + ((u >> 16) & 1u)) >> 16);   // RNE
}

__device__ static inline void async16(const void* g, void* l) {
    __builtin_amdgcn_global_load_lds(
        (const __attribute__((address_space(1))) void*)g,
        (__attribute__((address_space(3))) void*)l, 16, 0, 0);
}

// ---------------- Kernel B: emb -> bf16 + half-norms + zero accum ---------------
__global__ __launch_bounds__(256)
void emb_prep_kernel(const float* __restrict__ emb, unsigned short* __restrict__ eb,
                     float* __restrict__ hn, float* __restrict__ loss_accum) {
    if (blockIdx.x == 0 && threadIdx.x == 0) loss_accum[0] = 0.0f;
    int wave = (blockIdx.x * 256 + threadIdx.x) >> 6;   // 1024 waves, one per emb row
    int lane = threadIdx.x & 63;
    float4 v = reinterpret_cast<const float4*>(emb + (size_t)wave * DIM)[lane];
    float s = v.x * v.x + v.y * v.y + v.z * v.z + v.w * v.w;
    #pragma unroll
    for (int off = 32; off > 0; off >>= 1) s += __shfl_xor(s, off, 64);
    if (lane == 0) hn[wave] = 0.5f * s;
    ushort4 w = { f2bf(v.x), f2bf(v.y), f2bf(v.z), f2bf(v.w) };
    *reinterpret_cast<ushort4*>(eb + (size_t)wave * DIM + lane * 4) = w;
}

// ---------------- Fused kernel: convert + MFMA argmax + gather + loss -----------
// Block: 128 rows x ALL 1024 cols. 4 waves, 32 rows/wave.
// A (K=256) loaded fp32 straight from x into fragment layout, converted in-reg.
// B swept in 16 chunks of 64 cols, double-buffered via global_load_lds prefetch.
// Depth-3 register pipeline on B fragments (ds_read issued 2 ks ahead),
// setprio around MFMA clusters, readlane-based fully-unrolled gather epilogue,
// nontemporal out stores (via clang ext-vector f32x4).
// LDS: B bufs [0,32K)+[32K,64K); hn [64K,68K); idxs [68K..); partials.
__global__ __launch_bounds__(256, 2)
void vq_fused_kernel(const float* __restrict__ x, const float* __restrict__ emb,
                     const unsigned short* __restrict__ eb,
                     const float* __restrict__ hn,
                     float* __restrict__ out, float* __restrict__ loss_accum) {
    __shared__ __align__(16) char smem[70656];
    float* hns     = reinterpret_cast<float*>(smem + 65536);
    int*   idxs    = reinterpret_cast<int*>(smem + 69632);    // 128 ints
    float* partial = reinterpret_cast<float*>(smem + 70144);  // 4 floats

    const int t    = threadIdx.x;
    const int w    = t >> 6, lane = t & 63;
    const int q    = lane >> 4, l15 = lane & 15;
    const int n0   = blockIdx.x * 128;

    #pragma unroll
    for (int i = 0; i < 4; ++i) hns[t + i * 256] = hn[t + i * 256];

    // ---- per-thread B staging constants (swizzled) ----
    const unsigned short* egp[4];
    int ldsB[4];
    #pragma unroll
    for (int i = 0; i < 4; ++i) {
        int s  = i * 512 + t;
        int c  = s >> 5;
        int pk = (s & 24) | ((s ^ c) & 7);
        egp[i]  = eb + (size_t)c * DIM + pk * 8;
        ldsB[i] = (i * 512 + w * 64) * 16;
    }
    // prefetch B chunk 0 -> buf0 (in flight during the x load/convert below)
    #pragma unroll
    for (int i = 0; i < 4; ++i) async16(egp[i], smem + ldsB[i]);

    // ---- load x fp32 directly into A fragments, convert to bf16 ----
    // a[mt][ks] = x_bf16[row = w*32+mt*16+l15, cols (ks*4+q)*8 .. +7]
    bf16x8 a[2][8];
    const float* xrow = x + (size_t)(n0 + w * 32 + l15) * DIM + q * 8;
    #pragma unroll
    for (int mt = 0; mt < 2; ++mt) {
        #pragma unroll
        for (int ks = 0; ks < 8; ++ks) {
            const float4* p = reinterpret_cast<const float4*>(xrow + mt * 16 * DIM + ks * 32);
            float4 v0 = p[0], v1 = p[1];
            bf16x8 av;
            av[0] = (short)f2bf(v0.x); av[1] = (short)f2bf(v0.y);
            av[2] = (short)f2bf(v0.z); av[3] = (short)f2bf(v0.w);
            av[4] = (short)f2bf(v1.x); av[5] = (short)f2bf(v1.y);
            av[6] = (short)f2bf(v1.z); av[7] = (short)f2bf(v1.w);
            a[mt][ks] = av;
        }
    }

    // B-frag LDS offsets: col stride 512B; swizzle depends only on l15 (c&7==l15&7)
    int soff[8];
    #pragma unroll
    for (int ks = 0; ks < 8; ++ks) {
        int pk = ks * 4 + q;
        soff[ks] = ((pk & 24) | ((pk ^ l15) & 7)) * 16;
    }
    int cb[4];
    #pragma unroll
    for (int nt = 0; nt < 4; ++nt) cb[nt] = (nt * 16 + l15) * 512;

    float best[8];
    int   bidx[8];
    #pragma unroll
    for (int i = 0; i < 8; ++i) { best[i] = -1e30f; bidx[i] = 0; }

    for (int c = 0; c < 16; ++c) {
        __syncthreads();   // chunk c staged; prior readers of other buf done
        const char* buf = smem + (c & 1) * 32768;
        if (c < 15) {      // prefetch chunk c+1 into the buffer freed at the barrier
            int nb = ((c + 1) & 1) * 32768;
            #pragma unroll
            for (int i = 0; i < 4; ++i)
                async16(egp[i] + (c + 1) * 64 * DIM, smem + nb + ldsB[i]);
        }
        // hn loads first: latency hides under the bb preloads below
        float h[4];
        #pragma unroll
        for (int nt = 0; nt < 4; ++nt) h[nt] = -hns[c * 64 + nt * 16 + l15];

        // depth-3 register pipeline: bb[s] rotates, loads issued 2 ks ahead
        bf16x8 bb[3][4];
        #pragma unroll
        for (int i = 0; i < 4; ++i)
            bb[0][i] = *reinterpret_cast<const bf16x8*>(buf + cb[i] + soff[0]);
        #pragma unroll
        for (int i = 0; i < 4; ++i)
            bb[1][i] = *reinterpret_cast<const bf16x8*>(buf + cb[i] + soff[1]);

        f32x4 acc[2][4];
        #pragma unroll
        for (int nt = 0; nt < 4; ++nt) {
            f32x4 in4 = {h[nt], h[nt], h[nt], h[nt]};
            acc[0][nt] = in4; acc[1][nt] = in4;
        }
        #pragma unroll
        for (int ks = 0; ks < 8; ++ks) {
            if (ks < 6) {
                #pragma unroll
                for (int i = 0; i < 4; ++i)
                    bb[(ks + 2) % 3][i] =
                        *reinterpret_cast<const bf16x8*>(buf + cb[i] + soff[ks + 2]);
            }
            const bf16x8 b0 = bb[ks % 3][0], b1 = bb[ks % 3][1];
            const bf16x8 b2 = bb[ks % 3][2], b3 = bb[ks % 3][3];
            __builtin_amdgcn_s_setprio(1);
            acc[0][0] = __builtin_amdgcn_mfma_f32_16x16x32_bf16(a[0][ks], b0, acc[0][0], 0, 0, 0);
            acc[1][0] = __builtin_amdgcn_mfma_f32_16x16x32_bf16(a[1][ks], b0, acc[1][0], 0, 0, 0);
            acc[0][1] = __builtin_amdgcn_mfma_f32_16x16x32_bf16(a[0][ks], b1, acc[0][1], 0, 0, 0);
            acc[1][1] = __builtin_amdgcn_mfma_f32_16x16x32_bf16(a[1][ks], b1, acc[1][1], 0, 0, 0);
            acc[0][2] = __builtin_amdgcn_mfma_f32_16x16x32_bf16(a[0][ks], b2, acc[0][2], 0, 0, 0);
            acc[1][2] = __builtin_amdgcn_mfma_f32_16x16x32_bf16(a[1][ks], b2, acc[1][2], 0, 0, 0);
            acc[0][3] = __builtin_amdgcn_mfma_f32_16x16x32_bf16(a[0][ks], b3, acc[0][3], 0, 0, 0);
            acc[1][3] = __builtin_amdgcn_mfma_f32_16x16x32_bf16(a[1][ks], b3, acc[1][3], 0, 0, 0);
            __builtin_amdgcn_s_setprio(0);
        }
        // epilogue: scores already include -0.5||e||^2; cols ascend -> strict >
        #pragma unroll
        for (int nt = 0; nt < 4; ++nt) {
            int k = c * 64 + nt * 16 + l15;
            #pragma unroll
            for (int mt = 0; mt < 2; ++mt)
                #pragma unroll
                for (int r = 0; r < 4; ++r) {
                    float sc = acc[mt][nt][r];
                    int slot = mt * 4 + r;
                    if (sc > best[slot]) { best[slot] = sc; bidx[slot] = k; }
                }
        }
    }

    // butterfly argmax across the 16 l15 lanes (lowest index wins ties)
    #pragma unroll
    for (int slot = 0; slot < 8; ++slot) {
        float bs = best[slot]; int bi = bidx[slot];
        #pragma unroll
        for (int off = 8; off >= 1; off >>= 1) {
            float os = __shfl_xor(bs, off, 64);
            int   oi = __shfl_xor(bi, off, 64);
            if (os > bs || (os == bs && oi < bi)) { bs = os; bi = oi; }
        }
        if (l15 == 0) {
            int mt = slot >> 2, r = slot & 3;
            idxs[w * 32 + mt * 16 + q * 4 + r] = bi;
        }
    }

    // gather quantized rows (fp32 emb, L2/L3-resident), write output (nontemporal),
    // accumulate the loss DIRECTLY from fp32 x re-read (proven path).
    // One LDS read + readlane broadcast per row; full unroll for load batching.
    int myidx = idxs[w * 32 + (lane & 31)];
    float s = 0.0f;
    #pragma unroll
    for (int i = 0; i < 32; ++i) {
        int n = n0 + w * 32 + i;
        int k = __builtin_amdgcn_readlane(myidx, i);
        float4 qv = *reinterpret_cast<const float4*>(emb + (size_t)k * DIM + lane * 4);
        float4 xv = *reinterpret_cast<const float4*>(x + (size_t)n * DIM + lane * 4);
        __builtin_nontemporal_store(*reinterpret_cast<const f32x4*>(&qv),
            reinterpret_cast<f32x4*>(out + (size_t)n * DIM + lane * 4));
        float dx = qv.x - xv.x, dy = qv.y - xv.y, dz = qv.z - xv.z, dw = qv.w - xv.w;
        s += dx * dx + dy * dy + dz * dz + dw * dw;
    }
    #pragma unroll
    for (int off = 32; off > 0; off >>= 1) s += __shfl_xor(s, off, 64);
    if (lane == 0) partial[w] = s;
    __syncthreads();
    if (t == 0)
        atomicAdd(loss_accum, partial[0] + partial[1] + partial[2] + partial[3]);
}

// ---------------- finalize loss --------------------------------------------------
__global__ void finalize_kernel(const float* __restrict__ loss_accum,
                                float* __restrict__ out_loss) {
    if (threadIdx.x == 0)
        out_loss[0] = 1.25f * loss_accum[0] / 16777216.0f;
}

extern "C" void kernel_launch(void* const* d_in, const int* in_sizes, int n_in,
                              void* d_out, int out_size, void* d_ws, size_t ws_size,
                              hipStream_t stream) {
    const float* x   = reinterpret_cast<const float*>(d_in[0]);
    const float* emb = reinterpret_cast<const float*>(d_in[1]);
    float* out       = reinterpret_cast<float*>(d_out);
    float* loss_out  = out + (size_t)N_ROWS * DIM;

    char* ws = reinterpret_cast<char*>(d_ws);
    float*          loss_accum = reinterpret_cast<float*>(ws);            // 256 B
    float*          hn         = reinterpret_cast<float*>(ws + 4096);     // 4 KB
    unsigned short* eb         = reinterpret_cast<unsigned short*>(ws + 8192); // 512 KB

    emb_prep_kernel<<<K_EMB / 4, 256, 0, stream>>>(emb, eb, hn, loss_accum);
    vq_fused_kernel<<<N_ROWS / 128, 256, 0, stream>>>(x, emb, eb, hn, out, loss_accum);
    finalize_kernel<<<1, 64, 0, stream>>>(loss_accum, loss_out);
}